// Round 14
// baseline (992.515 us; speedup 1.0000x reference)
//
#include <hip/hip_runtime.h>
#include <hip/hip_fp16.h>
#include <stdint.h>

#define N_NODES 4096
#define BATCH   512
#define STEPS   120
#define LEAK    0.01f
#define NMASK   4095u
#define MAXG    19                 // max 4-slot groups per row (deg <= 76)
#define ALLOCG  20                 // +1 group so prefetch of g+1 stays in-bounds
#define NN4     N_NODES            // uint4 elements per group
#define SCHED_SLOTS 80             // >= MAXG*4

// ws layout (bytes):
#define OFF_DEG    0               // int[4096]
#define OFF_CURSOR 16384           // int[4096]
#define OFF_HIST   32768           // int[256]
#define OFF_CNT    33792           // int[256]
#define OFF_GMAX   34816           // int[64]   max degree per (band,slice)
#define OFF_BOUNDS 35072           // int[64]   group count per (band,slice)
#define OFF_START  35328           // int[256]  exclusive scan of hist
#define OFF_POS    36352           // int[4096] node -> permuted position
#define OFF_ORIG   52736           // int[4096] position -> node
#define OFF_PDEG   69632           // int[4096] position -> degree
#define OFF_E      86016           // u32 ELL [group][pos][4]  (NOT pre-zeroed)
#define WS_BYTES   (OFF_E + ALLOCG * N_NODES * 16)   // 1,396,736
#define ZERO_WORDS (OFF_E / 4)     // zero meta only; E fully managed by sched

__global__ void zero_ws(unsigned* __restrict__ p, int n) {
    int i = (int)(blockIdx.x * 1024 + threadIdx.x);
    if (i < n) p[i] = 0u;
}

// Wave-coalesced: shfl-reduce nz, one atomic per wave (wave's 256 floats lie
// within one row: 4096 % 256 == 0).
__global__ void count_deg(const float4* __restrict__ W4, int* __restrict__ deg) {
    int i = (int)(blockIdx.x * 256 + threadIdx.x);      // 4,194,304
    float4 w = W4[i];
    int nz = (w.x != 0.0f) + (w.y != 0.0f) + (w.z != 0.0f) + (w.w != 0.0f);
    #pragma unroll
    for (int o = 32; o > 0; o >>= 1) nz += __shfl_down(nz, o);
    if ((threadIdx.x & 63) == 0 && nz)
        atomicAdd(&deg[(i * 4) >> 12], nz);
}

__global__ void hist_deg(const int* __restrict__ deg, int* __restrict__ hist) {
    int t = (int)(blockIdx.x * 256 + threadIdx.x);
    int d = deg[t]; if (d > 255) d = 255;
    atomicAdd(&hist[d], 1);
}

__global__ void scan_start(const int* __restrict__ hist, int* __restrict__ start) {
    __shared__ int sm[256];
    int tid = (int)threadIdx.x;
    int v = hist[tid];
    sm[tid] = v;
    __syncthreads();
    for (int o = 1; o < 256; o <<= 1) {
        int u = (tid >= o) ? sm[tid - o] : 0;
        __syncthreads();
        sm[tid] += u;
        __syncthreads();
    }
    start[tid] = sm[tid] - v;               // exclusive scan (ascending degree)
}

// Counting-sort ranks by degree; thread tid owns positions {tid, 1024+tid,
// 2048+tid, 3072+tid} = ranks {q, 2047-q, 2048+q, 4095-q} (balanced sum).
__global__ void rank_assign(const int* __restrict__ deg,
                            const int* __restrict__ start,
                            int* __restrict__ cnt,
                            int* __restrict__ pos_of,
                            int* __restrict__ orig_of,
                            int* __restrict__ gmax,
                            int* __restrict__ pdeg) {
    int t = (int)(blockIdx.x * 256 + threadIdx.x);   // 4096 nodes
    int d = deg[t]; int dc = d > 255 ? 255 : d;
    int r = start[dc] + atomicAdd(&cnt[dc], 1);
    int p;
    if      (r < 1024) p = r;                        // band 0 (lightest)
    else if (r < 2048) p = 1024 + (2047 - r);        // band 1
    else if (r < 3072) p = 2048 + (r - 2048);        // band 2
    else               p = 3072 + (4095 - r);        // band 3 (heaviest)
    pos_of[t] = p;
    orig_of[p] = t;
    pdeg[p] = d;
    atomicMax(&gmax[p >> 6], d);                     // per (band,slice) max deg
}

// Min 4 groups (T >= 16): P(all 3 choices land in zero-capacity residues)
// stays small while cutting forced pads in light bands roughly in half vs
// the previous min-8.
__global__ void finalize_bounds(const int* __restrict__ gmax,
                                int* __restrict__ bounds) {
    int i = (int)threadIdx.x;                        // 64
    int g = (gmax[i] + 3) >> 2;
    if (g < 4)    g = 4;
    if (g > MAXG) g = MAXG;
    bounds[i] = g;
}

// scatter: payload [31:16] = f16(w), [15:2] = copyA byte offset (src pos * 4)
// Wave shfl-scan of per-thread nz -> one cursor atomic per wave (row is
// wave-uniform), each lane writes at base + exclusive prefix.
__global__ void scatter_edges(const float4* __restrict__ W4,
                              const int* __restrict__ pos_of,
                              int* __restrict__ cursor,
                              unsigned* __restrict__ E) {
    int i = (int)(blockIdx.x * 256 + threadIdx.x);   // 4,194,304
    float4 w = W4[i];
    float v[4] = {w.x, w.y, w.z, w.w};
    int nz = (v[0] != 0.0f) + (v[1] != 0.0f) + (v[2] != 0.0f) + (v[3] != 0.0f);
    int idx0 = i * 4;
    int t = idx0 >> 12;                              // wave-uniform
    int lane = (int)(threadIdx.x & 63);
    int inc = nz;
    #pragma unroll
    for (int o = 1; o < 64; o <<= 1) {
        int u = __shfl_up(inc, o);
        if (lane >= o) inc += u;
    }                                                // inclusive scan
    int base = 0;
    if (lane == 63 && inc > 0) base = atomicAdd(&cursor[t], inc);
    base = __shfl(base, 63);
    if (!nz) return;
    int k = base + inc - nz;                         // exclusive offset
    unsigned p = (unsigned)pos_of[t];
    #pragma unroll
    for (int j = 0; j < 4; ++j) {
        if (v[j] != 0.0f) {
            if (k < MAXG * 4) {
                unsigned sI = (unsigned)(idx0 + j) & NMASK;
                unsigned hw = (unsigned)__half_as_ushort(__float2half(v[j]));
                E[(((unsigned)(k >> 2) * NN4 + p) << 2) | (unsigned)(k & 3)]
                    = (hw << 16) | ((unsigned)pos_of[sI] << 2);
            }
            ++k;
        }
    }
}

// Copy index functions (permutation within each 32-block; per-block rotation
// decorrelates banks). copyA bank = i; copyB bank = i+j; copyC bank = i+2j+1
// (j = pos>>5). C never degenerates vs A; C vs B only when j%32==31.
__device__ __forceinline__ int idxB_of(int s) {
    return (s & ~31) | ((s + (s >> 5)) & 31);
}
__device__ __forceinline__ int idxC_of(int s) {
    return (s & ~31) | ((s + 2 * (s >> 5) + 1) & 31);
}

__device__ __forceinline__ void choices_of(unsigned s, unsigned lrot,
                                           int r[3], unsigned a[3]) {
    unsigned iB = (unsigned)idxB_of((int)s);
    unsigned iC = (unsigned)idxC_of((int)s);
    a[0] = s << 2;
    a[1] = 0x4000u | (iB << 2);
    a[2] = 0x8000u | (iC << 2);
    r[0] = (int)(((s  & 31u) - lrot) & 31u);
    r[1] = (int)(((iB & 31u) - lrot) & 31u);
    r[2] = (int)(((iC & 31u) - lrot) & 31u);
}

// Bank scheduler v7: as v6 (ring + 3-choice + depth-1 repair, LDS state) but
// reads exactly pdeg[p] staged edges (scatter packs them contiguously) so E
// needs no pre-zeroing and no w!=0 sentinel.
__global__ void __launch_bounds__(64)
bank_schedule(unsigned* __restrict__ E, const int* __restrict__ bounds,
              const int* __restrict__ pdeg) {
    __shared__ unsigned       slotP[64 * SCHED_SLOTS];   // 20 KB payloads
    __shared__ unsigned short slotS[64 * SCHED_SLOTS];   // 10 KB src positions
    __shared__ unsigned       stageb[64 * SCHED_SLOTS];  // 20 KB edge staging
    __shared__ int            usedb[64 * 32];            //  8 KB residue counts
    unsigned*       sp = &slotP[threadIdx.x * SCHED_SLOTS];
    unsigned short* ss = &slotS[threadIdx.x * SCHED_SLOTS];
    unsigned*       st = &stageb[threadIdx.x * SCHED_SLOTS];
    int*            us = &usedb[threadIdx.x * 32];
    int p = (int)(blockIdx.x * 64 + threadIdx.x);    // 0..4095
    int B = p >> 10, sl = (p >> 6) & 15;
    int T = bounds[B * 16 + sl] * 4;
    int pd = pdeg[p]; if (pd > T) pd = T;
    unsigned lrot = (unsigned)(p & 31);              // lane&31 == p&31

    // Phase A: stage E -> LDS (independent loads, pipelined)
    for (int t = 0; t < pd; ++t)
        st[t] = E[(((unsigned)(t >> 2) * NN4 + (unsigned)p) << 2) | (unsigned)(t & 3)];

    // Phase B: init
    for (int t = 0; t < T; ++t) { sp[t] = 0xFFFFFFFFu; ss[t] = 0xFFFF; }
    #pragma unroll
    for (int r = 0; r < 32; ++r) us[r] = 0;

    // Phase C: greedy max-slack placement; overflow packed back into st[]
    int novf = 0;
    for (int i = 0; i < pd; ++i) {
        unsigned e = st[i];
        unsigned s = (e >> 2) & NMASK;
        unsigned w = e & 0xFFFF0000u;
        int r[3]; unsigned a[3]; choices_of(s, lrot, r, a);
        int best = -1, smax = 0;
        #pragma unroll
        for (int c = 0; c < 3; ++c) {
            int slack = ((T + 31 - r[c]) >> 5) - us[r[c]];
            if (slack > smax) { smax = slack; best = c; }
        }
        if (best >= 0) {
            int q = r[best];
            sp[q + 32 * us[q]] = w | a[best];
            ss[q + 32 * us[q]] = (unsigned short)s;
            us[q]++;
        } else { st[novf++] = w | (s << 2); }
    }

    // Phase D: depth-1 augmenting repair; remnant re-packed into st[0..nrem)
    int nrem = 0;
    for (int i = 0; i < novf; ++i) {
        unsigned e = st[i];
        unsigned s = (e >> 2) & NMASK;
        unsigned w = e & 0xFFFF0000u;
        int r[3]; unsigned a[3]; choices_of(s, lrot, r, a);
        bool placed = false;
        for (int c = 0; c < 3 && !placed; ++c) {
            int q = r[c], cap = (T + 31 - q) >> 5;
            for (int k = 0; k < cap && !placed; ++k) {
                int t2 = q + 32 * k;
                unsigned s2 = ss[t2];
                if (s2 == 0xFFFF) continue;
                int r2[3]; unsigned a2[3]; choices_of(s2, lrot, r2, a2);
                #pragma unroll
                for (int c2 = 0; c2 < 3; ++c2) {
                    int q2 = r2[c2]; if (q2 == q) continue;
                    int cap2 = (T + 31 - q2) >> 5;
                    if (us[q2] < cap2) {
                        unsigned w2 = sp[t2] & 0xFFFF0000u;
                        sp[q2 + 32 * us[q2]] = w2 | a2[c2];
                        ss[q2 + 32 * us[q2]] = (unsigned short)s2;
                        us[q2]++;
                        sp[t2] = w | a[c]; ss[t2] = (unsigned short)s;
                        placed = true; break;
                    }
                }
            }
        }
        if (!placed) { st[nrem++] = e; }
    }

    // Phase E: fill leftovers (remnant overflow first, then nominal-bank
    // pads) and store back to E.
    int oi = 0;
    for (int t = 0; t < T; ++t) {
        if (sp[t] != 0xFFFFFFFFu) continue;
        if (oi < nrem) { sp[t] = st[oi++]; }
        else sp[t] = ((((unsigned)p & ~31u) | (((unsigned)p + (unsigned)t) & 31u)) << 2);
    }
    for (int t = 0; t < T; ++t)
        E[(((unsigned)(t >> 2) * NN4 + (unsigned)p) << 2) | (unsigned)(t & 3)] = sp[t];
}

__device__ __forceinline__ float mml_f(float x) {
    float y = (x < 0.0f) ? (LEAK * x) : x;
    if (x > 0.5f) y = 1.0f - 0.25f / x;              // x>0.5 => max(x,0.5)=x
    return y;
}
__device__ __forceinline__ __half2 mml_pack2(float ax, float ay) {
    return __floats2half2_rn(mml_f(ax), mml_f(ay));  // lo = col0, hi = col1
}

// acc.x += f16(hi16(u)) * f16(lo16(x));  acc.y += f16(hi16(u)) * f16(hi16(x))
#define EMIX(U, XW, AX, AY)                                                  \
    asm("v_fma_mix_f32 %0, %1, %2, %0 op_sel:[1,0,0] op_sel_hi:[1,1,0]"      \
        : "+v"(AX) : "v"(U), "v"(XW));                                       \
    asm("v_fma_mix_f32 %0, %1, %2, %0 op_sel:[1,1,0] op_sel_hi:[1,1,0]"      \
        : "+v"(AY) : "v"(U), "v"(XW));

#define EDGE4(C, S, AX, AY) {                                                \
    unsigned _x0 = *(const unsigned*)((const char*)(S) + ((C).x & 0xFFFCu)); \
    unsigned _x1 = *(const unsigned*)((const char*)(S) + ((C).y & 0xFFFCu)); \
    unsigned _x2 = *(const unsigned*)((const char*)(S) + ((C).z & 0xFFFCu)); \
    unsigned _x3 = *(const unsigned*)((const char*)(S) + ((C).w & 0xFFFCu)); \
    EMIX((C).x, _x0, AX, AY) EMIX((C).y, _x1, AX, AY)                        \
    EMIX((C).z, _x2, AX, AY) EMIX((C).w, _x3, AX, AY) }

// One step. Main loop interleaves all 4 bands to Gm (16 gathers in flight);
// tails are MERGED into one loop with wave-uniform per-band guards so
// multiple bands' gathers stay in flight (was: 4 serial tails with ILP=4).
// dst written to all three copies (B/C patterns are exact 2-lane/bank
// permutations: free).
#define STEP(S, D) {                                                         \
    float a0x = xb0.x, a0y = xb0.y, a1x = xb1.x, a1y = xb1.y;                \
    float a2x = xb2.x, a2y = xb2.y, a3x = xb3.x, a3y = xb3.y;                \
    uint4 c0 = B0[0], c1 = B1[0], c2 = B2[0], c3 = B3[0];                    \
    int g = 0;                                                               \
    _Pragma("unroll 2")                                                      \
    for (; g < Gm; ++g) {                                                    \
        uint4 n0 = B0[(size_t)(g + 1) * NN4], n1 = B1[(size_t)(g + 1) * NN4];\
        uint4 n2 = B2[(size_t)(g + 1) * NN4], n3 = B3[(size_t)(g + 1) * NN4];\
        EDGE4(c0, S, a0x, a0y) EDGE4(c1, S, a1x, a1y)                        \
        EDGE4(c2, S, a2x, a2y) EDGE4(c3, S, a3x, a3y)                        \
        c0 = n0; c1 = n1; c2 = n2; c3 = n3;                                  \
    }                                                                        \
    for (int h = g; h < Gx; ++h) {                                           \
        uint4 n0, n1, n2, n3;                                                \
        if (h < G0) n0 = B0[(size_t)(h + 1) * NN4];                          \
        if (h < G1) n1 = B1[(size_t)(h + 1) * NN4];                          \
        if (h < G2) n2 = B2[(size_t)(h + 1) * NN4];                          \
        if (h < G3) n3 = B3[(size_t)(h + 1) * NN4];                          \
        if (h < G0) { EDGE4(c0, S, a0x, a0y) c0 = n0; }                      \
        if (h < G1) { EDGE4(c1, S, a1x, a1y) c1 = n1; }                      \
        if (h < G2) { EDGE4(c2, S, a2x, a2y) c2 = n2; }                      \
        if (h < G3) { EDGE4(c3, S, a3x, a3y) c3 = n3; }                      \
    }                                                                        \
    __half2 v0 = mml_pack2(a0x, a0y), v1 = mml_pack2(a1x, a1y);              \
    __half2 v2 = mml_pack2(a2x, a2y), v3 = mml_pack2(a3x, a3y);              \
    (D)[tid]        = v0; (D)[4096 + ib0] = v0; (D)[8192 + ic0] = v0;        \
    (D)[1024 + tid] = v1; (D)[4096 + ib1] = v1; (D)[8192 + ic1] = v1;        \
    (D)[2048 + tid] = v2; (D)[4096 + ib2] = v2; (D)[8192 + ic2] = v2;        \
    (D)[3072 + tid] = v3; (D)[4096 + ib3] = v3; (D)[8192 + ic3] = v3;        \
    __syncthreads(); }

__global__ void __launch_bounds__(1024, 4)
iterate_kernel(const float* __restrict__ X_full,     // (512, 4096) row-major
               const float* __restrict__ bias,       // (4096)
               const unsigned* __restrict__ E,
               const int* __restrict__ bounds,       // [4][16]
               const int* __restrict__ orig_of,      // pos -> node
               float* __restrict__ out) {            // (512, 4096) row-major
    __shared__ __half2 sbuf[2 * 12288];              // 96 KB: 2 bufs x (A+B+C)
    __half2* buf0 = sbuf;
    __half2* buf1 = sbuf + 12288;

    const int tid  = (int)threadIdx.x;               // 0..1023
    const int colb = (int)blockIdx.x * 2;
    const int s    = tid >> 6;                       // wave slice 0..15
    const uint4* Eb = (const uint4*)E;

    const int G0 = bounds[s],      G1 = bounds[16 + s];
    const int G2 = bounds[32 + s], G3 = bounds[48 + s];
    const int Gm = min(min(G0, G1), min(G2, G3));
    const int Gx = max(max(G0, G1), max(G2, G3));

    const uint4* B0 = Eb + tid;
    const uint4* B1 = Eb + 1024 + tid;
    const uint4* B2 = Eb + 2048 + tid;
    const uint4* B3 = Eb + 3072 + tid;

    const int ib0 = idxB_of(tid),        ib1 = idxB_of(1024 + tid);
    const int ib2 = idxB_of(2048 + tid), ib3 = idxB_of(3072 + tid);
    const int ic0 = idxC_of(tid),        ic1 = idxC_of(1024 + tid);
    const int ic2 = idxC_of(2048 + tid), ic3 = idxC_of(3072 + tid);

    const int t0 = orig_of[tid],        t1 = orig_of[1024 + tid];
    const int t2 = orig_of[2048 + tid], t3 = orig_of[3072 + tid];

    const float* x0r = X_full + (size_t)colb * N_NODES;
    const float* x1r = x0r + N_NODES;
    float b0 = bias[t0], b1 = bias[t1], b2 = bias[t2], b3 = bias[t3];
    float2 xb0 = make_float2(x0r[t0] + b0, x1r[t0] + b0);
    float2 xb1 = make_float2(x0r[t1] + b1, x1r[t1] + b1);
    float2 xb2 = make_float2(x0r[t2] + b2, x1r[t2] + b2);
    float2 xb3 = make_float2(x0r[t3] + b3, x1r[t3] + b3);

    // X1 = mml(X_bias) into buf0 (all three copies)
    {
        __half2 v0 = mml_pack2(xb0.x, xb0.y), v1 = mml_pack2(xb1.x, xb1.y);
        __half2 v2 = mml_pack2(xb2.x, xb2.y), v3 = mml_pack2(xb3.x, xb3.y);
        buf0[tid]        = v0; buf0[4096 + ib0] = v0; buf0[8192 + ic0] = v0;
        buf0[1024 + tid] = v1; buf0[4096 + ib1] = v1; buf0[8192 + ic1] = v1;
        buf0[2048 + tid] = v2; buf0[4096 + ib2] = v2; buf0[8192 + ic2] = v2;
        buf0[3072 + tid] = v3; buf0[4096 + ib3] = v3; buf0[8192 + ic3] = v3;
    }
    __syncthreads();

    // 119 more steps: 59 x (A->B, B->A) + final A->B; result in buf1
    #pragma unroll 1
    for (int p = 0; p < 59; ++p) {
        STEP(buf0, buf1)
        STEP(buf1, buf0)
    }
    STEP(buf0, buf1)

    __half2 f0 = buf1[tid],        f1 = buf1[1024 + tid];
    __half2 f2 = buf1[2048 + tid], f3 = buf1[3072 + tid];
    float* o0 = out + (size_t)colb * N_NODES;
    float* o1 = o0 + N_NODES;
    o0[t0] = __low2float(f0);  o0[t1] = __low2float(f1);
    o0[t2] = __low2float(f2);  o0[t3] = __low2float(f3);
    o1[t0] = __high2float(f0); o1[t1] = __high2float(f1);
    o1[t2] = __high2float(f2); o1[t3] = __high2float(f3);
}

extern "C" void kernel_launch(void* const* d_in, const int* in_sizes, int n_in,
                              void* d_out, int out_size, void* d_ws, size_t ws_size,
                              hipStream_t stream) {
    const float* X_full = nullptr;
    const float* W      = nullptr;
    const float* bias   = nullptr;
    for (int i = 0; i < n_in; ++i) {
        if      (in_sizes[i] == N_NODES * N_NODES) W      = (const float*)d_in[i];
        else if (in_sizes[i] == BATCH * N_NODES)   X_full = (const float*)d_in[i];
        else if (in_sizes[i] == N_NODES)           bias   = (const float*)d_in[i];
    }

    char* ws = (char*)d_ws;
    int*      deg    = (int*)(ws + OFF_DEG);
    int*      cursor = (int*)(ws + OFF_CURSOR);
    int*      hist   = (int*)(ws + OFF_HIST);
    int*      start  = (int*)(ws + OFF_START);
    int*      cnt    = (int*)(ws + OFF_CNT);
    int*      gmax   = (int*)(ws + OFF_GMAX);
    int*      bounds = (int*)(ws + OFF_BOUNDS);
    int*      pos_of = (int*)(ws + OFF_POS);
    int*      orig   = (int*)(ws + OFF_ORIG);
    int*      pdeg   = (int*)(ws + OFF_PDEG);
    unsigned* E      = (unsigned*)(ws + OFF_E);

    zero_ws        <<<(ZERO_WORDS + 1023) / 1024, 1024, 0, stream>>>((unsigned*)ws, ZERO_WORDS);
    count_deg      <<<N_NODES * N_NODES / 4 / 256, 256, 0, stream>>>((const float4*)W, deg);
    hist_deg       <<<N_NODES / 256, 256, 0, stream>>>(deg, hist);
    scan_start     <<<1, 256, 0, stream>>>(hist, start);
    rank_assign    <<<N_NODES / 256, 256, 0, stream>>>(deg, start, cnt, pos_of, orig, gmax, pdeg);
    finalize_bounds<<<1, 64, 0, stream>>>(gmax, bounds);
    scatter_edges  <<<N_NODES * N_NODES / 4 / 256, 256, 0, stream>>>((const float4*)W, pos_of, cursor, E);
    bank_schedule  <<<N_NODES / 64, 64, 0, stream>>>(E, bounds, pdeg);
    iterate_kernel <<<BATCH / 2, 1024, 0, stream>>>(X_full, bias, E, bounds, orig,
                                                    (float*)d_out);
}

// Round 15
// 932.486 us; speedup vs baseline: 1.0644x; 1.0644x over previous
//
#include <hip/hip_runtime.h>
#include <hip/hip_fp16.h>
#include <stdint.h>

#define N_NODES 4096
#define BATCH   512
#define STEPS   120
#define LEAK    0.01f
#define NMASK   4095u
#define MAXG    19                 // max 4-slot groups per row (deg <= 76)
#define ALLOCG  20                 // +1 group so prefetch of g+1 stays in-bounds
#define NN4     N_NODES            // uint4 elements per group
#define SCHED_SLOTS 80             // >= MAXG*4

// ws layout (bytes):
#define OFF_DEG    0               // int[4096]
#define OFF_CURSOR 16384           // int[4096]
#define OFF_HIST   32768           // int[256]
#define OFF_CNT    33792           // int[256]
#define OFF_GMAX   34816           // int[64]   max degree per (band,slice)
#define OFF_BOUNDS 35072           // int[64]   group count per (band,slice)
#define OFF_START  35328           // int[256]  exclusive scan of hist
#define OFF_POS    36352           // int[4096] node -> permuted position
#define OFF_ORIG   52736           // int[4096] position -> node
#define OFF_PDEG   69632           // int[4096] position -> degree
#define OFF_E      86016           // u32 ELL [group][pos][4]  (NOT pre-zeroed)
#define WS_BYTES   (OFF_E + ALLOCG * N_NODES * 16)   // 1,396,736
#define ZERO_WORDS (OFF_E / 4)     // zero meta only; E fully managed by sched

__global__ void zero_ws(unsigned* __restrict__ p, int n) {
    int i = (int)(blockIdx.x * 1024 + threadIdx.x);
    if (i < n) p[i] = 0u;
}

// Wave-coalesced: shfl-reduce nz, one atomic per wave (wave's 256 floats lie
// within one row: 4096 % 256 == 0).
__global__ void count_deg(const float4* __restrict__ W4, int* __restrict__ deg) {
    int i = (int)(blockIdx.x * 256 + threadIdx.x);      // 4,194,304
    float4 w = W4[i];
    int nz = (w.x != 0.0f) + (w.y != 0.0f) + (w.z != 0.0f) + (w.w != 0.0f);
    #pragma unroll
    for (int o = 32; o > 0; o >>= 1) nz += __shfl_down(nz, o);
    if ((threadIdx.x & 63) == 0 && nz)
        atomicAdd(&deg[(i * 4) >> 12], nz);
}

__global__ void hist_deg(const int* __restrict__ deg, int* __restrict__ hist) {
    int t = (int)(blockIdx.x * 256 + threadIdx.x);
    int d = deg[t]; if (d > 255) d = 255;
    atomicAdd(&hist[d], 1);
}

__global__ void scan_start(const int* __restrict__ hist, int* __restrict__ start) {
    __shared__ int sm[256];
    int tid = (int)threadIdx.x;
    int v = hist[tid];
    sm[tid] = v;
    __syncthreads();
    for (int o = 1; o < 256; o <<= 1) {
        int u = (tid >= o) ? sm[tid - o] : 0;
        __syncthreads();
        sm[tid] += u;
        __syncthreads();
    }
    start[tid] = sm[tid] - v;               // exclusive scan (ascending degree)
}

// Counting-sort ranks by degree; thread tid owns positions {tid, 1024+tid,
// 2048+tid, 3072+tid} = ranks {q, 2047-q, 2048+q, 4095-q} (balanced sum).
__global__ void rank_assign(const int* __restrict__ deg,
                            const int* __restrict__ start,
                            int* __restrict__ cnt,
                            int* __restrict__ pos_of,
                            int* __restrict__ orig_of,
                            int* __restrict__ gmax,
                            int* __restrict__ pdeg) {
    int t = (int)(blockIdx.x * 256 + threadIdx.x);   // 4096 nodes
    int d = deg[t]; int dc = d > 255 ? 255 : d;
    int r = start[dc] + atomicAdd(&cnt[dc], 1);
    int p;
    if      (r < 1024) p = r;                        // band 0 (lightest)
    else if (r < 2048) p = 1024 + (2047 - r);        // band 1
    else if (r < 3072) p = 2048 + (r - 2048);        // band 2
    else               p = 3072 + (4095 - r);        // band 3 (heaviest)
    pos_of[t] = p;
    orig_of[p] = t;
    pdeg[p] = d;
    atomicMax(&gmax[p >> 6], d);                     // per (band,slice) max deg
}

// Min 6 groups (T >= 24): zero-capacity residues = 8 -> forced overflow only
// (8/32)^3 = 1.6% of band-0 edges, while saving ~8 pad slots/thread vs min-8
// in the lightest slices. (min-4 raised conflicts 0.95e8 -> 1.14e8: too far.)
__global__ void finalize_bounds(const int* __restrict__ gmax,
                                int* __restrict__ bounds) {
    int i = (int)threadIdx.x;                        // 64
    int g = (gmax[i] + 3) >> 2;
    if (g < 6)    g = 6;
    if (g > MAXG) g = MAXG;
    bounds[i] = g;
}

// scatter: payload [31:16] = f16(w), [15:2] = copyA byte offset (src pos * 4)
// Wave shfl-scan of per-thread nz -> one cursor atomic per wave (row is
// wave-uniform), each lane writes at base + exclusive prefix.
__global__ void scatter_edges(const float4* __restrict__ W4,
                              const int* __restrict__ pos_of,
                              int* __restrict__ cursor,
                              unsigned* __restrict__ E) {
    int i = (int)(blockIdx.x * 256 + threadIdx.x);   // 4,194,304
    float4 w = W4[i];
    float v[4] = {w.x, w.y, w.z, w.w};
    int nz = (v[0] != 0.0f) + (v[1] != 0.0f) + (v[2] != 0.0f) + (v[3] != 0.0f);
    int idx0 = i * 4;
    int t = idx0 >> 12;                              // wave-uniform
    int lane = (int)(threadIdx.x & 63);
    int inc = nz;
    #pragma unroll
    for (int o = 1; o < 64; o <<= 1) {
        int u = __shfl_up(inc, o);
        if (lane >= o) inc += u;
    }                                                // inclusive scan
    int base = 0;
    if (lane == 63 && inc > 0) base = atomicAdd(&cursor[t], inc);
    base = __shfl(base, 63);
    if (!nz) return;
    int k = base + inc - nz;                         // exclusive offset
    unsigned p = (unsigned)pos_of[t];
    #pragma unroll
    for (int j = 0; j < 4; ++j) {
        if (v[j] != 0.0f) {
            if (k < MAXG * 4) {
                unsigned sI = (unsigned)(idx0 + j) & NMASK;
                unsigned hw = (unsigned)__half_as_ushort(__float2half(v[j]));
                E[(((unsigned)(k >> 2) * NN4 + p) << 2) | (unsigned)(k & 3)]
                    = (hw << 16) | ((unsigned)pos_of[sI] << 2);
            }
            ++k;
        }
    }
}

// Copy index functions (permutation within each 32-block; per-block rotation
// decorrelates banks). copyA bank = i; copyB bank = i+j; copyC bank = i+2j+1
// (j = pos>>5). C never degenerates vs A; C vs B only when j%32==31.
__device__ __forceinline__ int idxB_of(int s) {
    return (s & ~31) | ((s + (s >> 5)) & 31);
}
__device__ __forceinline__ int idxC_of(int s) {
    return (s & ~31) | ((s + 2 * (s >> 5) + 1) & 31);
}

__device__ __forceinline__ void choices_of(unsigned s, unsigned lrot,
                                           int r[3], unsigned a[3]) {
    unsigned iB = (unsigned)idxB_of((int)s);
    unsigned iC = (unsigned)idxC_of((int)s);
    a[0] = s << 2;
    a[1] = 0x4000u | (iB << 2);
    a[2] = 0x8000u | (iC << 2);
    r[0] = (int)(((s  & 31u) - lrot) & 31u);
    r[1] = (int)(((iB & 31u) - lrot) & 31u);
    r[2] = (int)(((iC & 31u) - lrot) & 31u);
}

// Bank scheduler v7: ring + 3-choice + depth-1 repair, all state in LDS;
// reads exactly pdeg[p] staged edges (scatter packs them contiguously) so E
// needs no pre-zeroing and no w!=0 sentinel.
__global__ void __launch_bounds__(64)
bank_schedule(unsigned* __restrict__ E, const int* __restrict__ bounds,
              const int* __restrict__ pdeg) {
    __shared__ unsigned       slotP[64 * SCHED_SLOTS];   // 20 KB payloads
    __shared__ unsigned short slotS[64 * SCHED_SLOTS];   // 10 KB src positions
    __shared__ unsigned       stageb[64 * SCHED_SLOTS];  // 20 KB edge staging
    __shared__ int            usedb[64 * 32];            //  8 KB residue counts
    unsigned*       sp = &slotP[threadIdx.x * SCHED_SLOTS];
    unsigned short* ss = &slotS[threadIdx.x * SCHED_SLOTS];
    unsigned*       st = &stageb[threadIdx.x * SCHED_SLOTS];
    int*            us = &usedb[threadIdx.x * 32];
    int p = (int)(blockIdx.x * 64 + threadIdx.x);    // 0..4095
    int B = p >> 10, sl = (p >> 6) & 15;
    int T = bounds[B * 16 + sl] * 4;
    int pd = pdeg[p]; if (pd > T) pd = T;
    unsigned lrot = (unsigned)(p & 31);              // lane&31 == p&31

    // Phase A: stage E -> LDS (independent loads, pipelined)
    for (int t = 0; t < pd; ++t)
        st[t] = E[(((unsigned)(t >> 2) * NN4 + (unsigned)p) << 2) | (unsigned)(t & 3)];

    // Phase B: init
    for (int t = 0; t < T; ++t) { sp[t] = 0xFFFFFFFFu; ss[t] = 0xFFFF; }
    #pragma unroll
    for (int r = 0; r < 32; ++r) us[r] = 0;

    // Phase C: greedy max-slack placement; overflow packed back into st[]
    int novf = 0;
    for (int i = 0; i < pd; ++i) {
        unsigned e = st[i];
        unsigned s = (e >> 2) & NMASK;
        unsigned w = e & 0xFFFF0000u;
        int r[3]; unsigned a[3]; choices_of(s, lrot, r, a);
        int best = -1, smax = 0;
        #pragma unroll
        for (int c = 0; c < 3; ++c) {
            int slack = ((T + 31 - r[c]) >> 5) - us[r[c]];
            if (slack > smax) { smax = slack; best = c; }
        }
        if (best >= 0) {
            int q = r[best];
            sp[q + 32 * us[q]] = w | a[best];
            ss[q + 32 * us[q]] = (unsigned short)s;
            us[q]++;
        } else { st[novf++] = w | (s << 2); }
    }

    // Phase D: depth-1 augmenting repair; remnant re-packed into st[0..nrem)
    int nrem = 0;
    for (int i = 0; i < novf; ++i) {
        unsigned e = st[i];
        unsigned s = (e >> 2) & NMASK;
        unsigned w = e & 0xFFFF0000u;
        int r[3]; unsigned a[3]; choices_of(s, lrot, r, a);
        bool placed = false;
        for (int c = 0; c < 3 && !placed; ++c) {
            int q = r[c], cap = (T + 31 - q) >> 5;
            for (int k = 0; k < cap && !placed; ++k) {
                int t2 = q + 32 * k;
                unsigned s2 = ss[t2];
                if (s2 == 0xFFFF) continue;
                int r2[3]; unsigned a2[3]; choices_of(s2, lrot, r2, a2);
                #pragma unroll
                for (int c2 = 0; c2 < 3; ++c2) {
                    int q2 = r2[c2]; if (q2 == q) continue;
                    int cap2 = (T + 31 - q2) >> 5;
                    if (us[q2] < cap2) {
                        unsigned w2 = sp[t2] & 0xFFFF0000u;
                        sp[q2 + 32 * us[q2]] = w2 | a2[c2];
                        ss[q2 + 32 * us[q2]] = (unsigned short)s2;
                        us[q2]++;
                        sp[t2] = w | a[c]; ss[t2] = (unsigned short)s;
                        placed = true; break;
                    }
                }
            }
        }
        if (!placed) { st[nrem++] = e; }
    }

    // Phase E: fill leftovers (remnant overflow first, then nominal-bank
    // pads) and store back to E.
    int oi = 0;
    for (int t = 0; t < T; ++t) {
        if (sp[t] != 0xFFFFFFFFu) continue;
        if (oi < nrem) { sp[t] = st[oi++]; }
        else sp[t] = ((((unsigned)p & ~31u) | (((unsigned)p + (unsigned)t) & 31u)) << 2);
    }
    for (int t = 0; t < T; ++t)
        E[(((unsigned)(t >> 2) * NN4 + (unsigned)p) << 2) | (unsigned)(t & 3)] = sp[t];
}

__device__ __forceinline__ float mml_f(float x) {
    float y = (x < 0.0f) ? (LEAK * x) : x;
    if (x > 0.5f) y = 1.0f - 0.25f / x;              // x>0.5 => max(x,0.5)=x
    return y;
}
__device__ __forceinline__ __half2 mml_pack2(float ax, float ay) {
    return __floats2half2_rn(mml_f(ax), mml_f(ay));  // lo = col0, hi = col1
}

// acc.x += f16(hi16(u)) * f16(lo16(x));  acc.y += f16(hi16(u)) * f16(hi16(x))
#define EMIX(U, XW, AX, AY)                                                  \
    asm("v_fma_mix_f32 %0, %1, %2, %0 op_sel:[1,0,0] op_sel_hi:[1,1,0]"      \
        : "+v"(AX) : "v"(U), "v"(XW));                                       \
    asm("v_fma_mix_f32 %0, %1, %2, %0 op_sel:[1,1,0] op_sel_hi:[1,1,0]"      \
        : "+v"(AY) : "v"(U), "v"(XW));

#define EDGE4(C, S, AX, AY) {                                                \
    unsigned _x0 = *(const unsigned*)((const char*)(S) + ((C).x & 0xFFFCu)); \
    unsigned _x1 = *(const unsigned*)((const char*)(S) + ((C).y & 0xFFFCu)); \
    unsigned _x2 = *(const unsigned*)((const char*)(S) + ((C).z & 0xFFFCu)); \
    unsigned _x3 = *(const unsigned*)((const char*)(S) + ((C).w & 0xFFFCu)); \
    EMIX((C).x, _x0, AX, AY) EMIX((C).y, _x1, AX, AY)                        \
    EMIX((C).z, _x2, AX, AY) EMIX((C).w, _x3, AX, AY) }

// One step (R13 form — serial short tails, lowest VGPR / best measured).
// Main loop interleaves all 4 bands to Gm (16 gathers in flight); dst
// written to all three copies (B/C patterns are exact 2-lane/bank
// permutations: free).
#define STEP(S, D) {                                                         \
    float a0x = xb0.x, a0y = xb0.y, a1x = xb1.x, a1y = xb1.y;                \
    float a2x = xb2.x, a2y = xb2.y, a3x = xb3.x, a3y = xb3.y;                \
    uint4 c0 = B0[0], c1 = B1[0], c2 = B2[0], c3 = B3[0];                    \
    int g = 0;                                                               \
    for (; g < Gm; ++g) {                                                    \
        uint4 n0 = B0[(size_t)(g + 1) * NN4], n1 = B1[(size_t)(g + 1) * NN4];\
        uint4 n2 = B2[(size_t)(g + 1) * NN4], n3 = B3[(size_t)(g + 1) * NN4];\
        EDGE4(c0, S, a0x, a0y) EDGE4(c1, S, a1x, a1y)                        \
        EDGE4(c2, S, a2x, a2y) EDGE4(c3, S, a3x, a3y)                        \
        c0 = n0; c1 = n1; c2 = n2; c3 = n3;                                  \
    }                                                                        \
    for (int h = g; h < G0; ++h) {                                           \
        uint4 n = B0[(size_t)(h + 1) * NN4]; EDGE4(c0, S, a0x, a0y) c0 = n; }\
    for (int h = g; h < G1; ++h) {                                           \
        uint4 n = B1[(size_t)(h + 1) * NN4]; EDGE4(c1, S, a1x, a1y) c1 = n; }\
    for (int h = g; h < G2; ++h) {                                           \
        uint4 n = B2[(size_t)(h + 1) * NN4]; EDGE4(c2, S, a2x, a2y) c2 = n; }\
    for (int h = g; h < G3; ++h) {                                           \
        uint4 n = B3[(size_t)(h + 1) * NN4]; EDGE4(c3, S, a3x, a3y) c3 = n; }\
    __half2 v0 = mml_pack2(a0x, a0y), v1 = mml_pack2(a1x, a1y);              \
    __half2 v2 = mml_pack2(a2x, a2y), v3 = mml_pack2(a3x, a3y);              \
    (D)[tid]        = v0; (D)[4096 + ib0] = v0; (D)[8192 + ic0] = v0;        \
    (D)[1024 + tid] = v1; (D)[4096 + ib1] = v1; (D)[8192 + ic1] = v1;        \
    (D)[2048 + tid] = v2; (D)[4096 + ib2] = v2; (D)[8192 + ic2] = v2;        \
    (D)[3072 + tid] = v3; (D)[4096 + ib3] = v3; (D)[8192 + ic3] = v3;        \
    __syncthreads(); }

__global__ void __launch_bounds__(1024, 4)
iterate_kernel(const float* __restrict__ X_full,     // (512, 4096) row-major
               const float* __restrict__ bias,       // (4096)
               const unsigned* __restrict__ E,
               const int* __restrict__ bounds,       // [4][16]
               const int* __restrict__ orig_of,      // pos -> node
               float* __restrict__ out) {            // (512, 4096) row-major
    __shared__ __half2 sbuf[2 * 12288];              // 96 KB: 2 bufs x (A+B+C)
    __half2* buf0 = sbuf;
    __half2* buf1 = sbuf + 12288;

    const int tid  = (int)threadIdx.x;               // 0..1023
    const int colb = (int)blockIdx.x * 2;
    const int s    = tid >> 6;                       // wave slice 0..15
    const uint4* Eb = (const uint4*)E;

    const int G0 = bounds[s],      G1 = bounds[16 + s];
    const int G2 = bounds[32 + s], G3 = bounds[48 + s];
    const int Gm = min(min(G0, G1), min(G2, G3));

    const uint4* B0 = Eb + tid;
    const uint4* B1 = Eb + 1024 + tid;
    const uint4* B2 = Eb + 2048 + tid;
    const uint4* B3 = Eb + 3072 + tid;

    const int ib0 = idxB_of(tid),        ib1 = idxB_of(1024 + tid);
    const int ib2 = idxB_of(2048 + tid), ib3 = idxB_of(3072 + tid);
    const int ic0 = idxC_of(tid),        ic1 = idxC_of(1024 + tid);
    const int ic2 = idxC_of(2048 + tid), ic3 = idxC_of(3072 + tid);

    const int t0 = orig_of[tid],        t1 = orig_of[1024 + tid];
    const int t2 = orig_of[2048 + tid], t3 = orig_of[3072 + tid];

    const float* x0r = X_full + (size_t)colb * N_NODES;
    const float* x1r = x0r + N_NODES;
    float b0 = bias[t0], b1 = bias[t1], b2 = bias[t2], b3 = bias[t3];
    float2 xb0 = make_float2(x0r[t0] + b0, x1r[t0] + b0);
    float2 xb1 = make_float2(x0r[t1] + b1, x1r[t1] + b1);
    float2 xb2 = make_float2(x0r[t2] + b2, x1r[t2] + b2);
    float2 xb3 = make_float2(x0r[t3] + b3, x1r[t3] + b3);

    // X1 = mml(X_bias) into buf0 (all three copies)
    {
        __half2 v0 = mml_pack2(xb0.x, xb0.y), v1 = mml_pack2(xb1.x, xb1.y);
        __half2 v2 = mml_pack2(xb2.x, xb2.y), v3 = mml_pack2(xb3.x, xb3.y);
        buf0[tid]        = v0; buf0[4096 + ib0] = v0; buf0[8192 + ic0] = v0;
        buf0[1024 + tid] = v1; buf0[4096 + ib1] = v1; buf0[8192 + ic1] = v1;
        buf0[2048 + tid] = v2; buf0[4096 + ib2] = v2; buf0[8192 + ic2] = v2;
        buf0[3072 + tid] = v3; buf0[4096 + ib3] = v3; buf0[8192 + ic3] = v3;
    }
    __syncthreads();

    // 119 more steps: 59 x (A->B, B->A) + final A->B; result in buf1
    #pragma unroll 1
    for (int p = 0; p < 59; ++p) {
        STEP(buf0, buf1)
        STEP(buf1, buf0)
    }
    STEP(buf0, buf1)

    __half2 f0 = buf1[tid],        f1 = buf1[1024 + tid];
    __half2 f2 = buf1[2048 + tid], f3 = buf1[3072 + tid];
    float* o0 = out + (size_t)colb * N_NODES;
    float* o1 = o0 + N_NODES;
    o0[t0] = __low2float(f0);  o0[t1] = __low2float(f1);
    o0[t2] = __low2float(f2);  o0[t3] = __low2float(f3);
    o1[t0] = __high2float(f0); o1[t1] = __high2float(f1);
    o1[t2] = __high2float(f2); o1[t3] = __high2float(f3);
}

extern "C" void kernel_launch(void* const* d_in, const int* in_sizes, int n_in,
                              void* d_out, int out_size, void* d_ws, size_t ws_size,
                              hipStream_t stream) {
    const float* X_full = nullptr;
    const float* W      = nullptr;
    const float* bias   = nullptr;
    for (int i = 0; i < n_in; ++i) {
        if      (in_sizes[i] == N_NODES * N_NODES) W      = (const float*)d_in[i];
        else if (in_sizes[i] == BATCH * N_NODES)   X_full = (const float*)d_in[i];
        else if (in_sizes[i] == N_NODES)           bias   = (const float*)d_in[i];
    }

    char* ws = (char*)d_ws;
    int*      deg    = (int*)(ws + OFF_DEG);
    int*      cursor = (int*)(ws + OFF_CURSOR);
    int*      hist   = (int*)(ws + OFF_HIST);
    int*      start  = (int*)(ws + OFF_START);
    int*      cnt    = (int*)(ws + OFF_CNT);
    int*      gmax   = (int*)(ws + OFF_GMAX);
    int*      bounds = (int*)(ws + OFF_BOUNDS);
    int*      pos_of = (int*)(ws + OFF_POS);
    int*      orig   = (int*)(ws + OFF_ORIG);
    int*      pdeg   = (int*)(ws + OFF_PDEG);
    unsigned* E      = (unsigned*)(ws + OFF_E);

    zero_ws        <<<(ZERO_WORDS + 1023) / 1024, 1024, 0, stream>>>((unsigned*)ws, ZERO_WORDS);
    count_deg      <<<N_NODES * N_NODES / 4 / 256, 256, 0, stream>>>((const float4*)W, deg);
    hist_deg       <<<N_NODES / 256, 256, 0, stream>>>(deg, hist);
    scan_start     <<<1, 256, 0, stream>>>(hist, start);
    rank_assign    <<<N_NODES / 256, 256, 0, stream>>>(deg, start, cnt, pos_of, orig, gmax, pdeg);
    finalize_bounds<<<1, 64, 0, stream>>>(gmax, bounds);
    scatter_edges  <<<N_NODES * N_NODES / 4 / 256, 256, 0, stream>>>((const float4*)W, pos_of, cursor, E);
    bank_schedule  <<<N_NODES / 64, 64, 0, stream>>>(E, bounds, pdeg);
    iterate_kernel <<<BATCH / 2, 1024, 0, stream>>>(X_full, bias, E, bounds, orig,
                                                    (float*)d_out);
}